// Round 5
// baseline (757.630 us; speedup 1.0000x reference)
//
#include <hip/hip_runtime.h>

// Gemma3nAttention: hidden(2,2048,2048) fp32 -> qkv gemm -> per-head rmsnorm ->
// rope -> GQA causal attention (no softmax scale!) -> out-proj -> (2,2048,2048) fp32.
// R4: flash_attn restructured. Old: 4-wave blocks, K/V staged in LDS, 2 barriers
// per 32-key tile -> latency-bound (MfmaUtil 7.6%, 188us). New: 1 wave = 16 q
// rows, NO barriers, K/V read straight from global (L1/L2-resident: K+V per
// (b,kv) = 2MB, GQA 4x reuse), 64-key tiles, LDS only for the 2.3KB per-wave
// P C->A transpose (same-wave DS ops are HW-ordered).

#define HID  2048
#define NH   8
#define NKV  2
#define HD   256
#define SB   2048
#define BB   2
#define MTOK (BB * SB)                 // 4096
#define NQKV ((NH + 2 * NKV) * HD)     // 3072

typedef _Float16  f16x8 __attribute__((ext_vector_type(8)));
typedef float     f32x4 __attribute__((ext_vector_type(4)));

__device__ __forceinline__ unsigned short f2h(float f) {
  _Float16 h = (_Float16)f;
  return __builtin_bit_cast(unsigned short, h);
}

// async global->LDS, 16B per lane (m97/m104): LDS dest = wave-uniform base +
// lane*16; our mapping is exactly base+lane*16 by construction.
__device__ __forceinline__ void async_copy16(const unsigned short* g, unsigned short* l) {
  __builtin_amdgcn_global_load_lds(
      (const __attribute__((address_space(1))) unsigned int*)g,
      (__attribute__((address_space(3))) unsigned int*)l, 16, 0, 0);
}

// chunk-column swizzle applied on the global-fetch side (LDS stays flat so
// global_load_lds still works); read side XORs the same pattern.
__device__ __forceinline__ int swz4(int r) { return (r + (r >> 2)) & 3; }

// ---------------------------------------------------------------------------
// GEMM: C[M][N] = A[M][K] * Bt[N][K]^T, fp16 in, fp32 accum.
// OUT_MODE: 0 = fp16(u16), 2 = fp32(float).
// 128x128 tile, BK=32, 4 waves of 64x64 (4x4 mfma_f32_16x16x32_f16). m97 shape.
// ---------------------------------------------------------------------------
template <int OUT_MODE>
__global__ __launch_bounds__(256) void gemm_bt(const unsigned short* __restrict__ A,
                                               const unsigned short* __restrict__ Bt,
                                               void* __restrict__ Cg,
                                               int M, int N, int K) {
  __shared__ unsigned short Ash[128 * 32];
  __shared__ unsigned short Bsh[128 * 32];
  const int t = threadIdx.x;
  const int lane = t & 63, w = t >> 6;
  const int quad = lane >> 4, m15 = lane & 15;
  const int wm = w >> 1, wn = w & 1;
  const int m0 = blockIdx.y * 128, n0 = blockIdx.x * 128;

  const int rowS0 = t >> 2, rowS1 = rowS0 + 64;
  const int slot = t & 3;
  const int g0 = (slot ^ swz4(rowS0)) * 8;
  const int g1 = (slot ^ swz4(rowS1)) * 8;
  const unsigned short* Ag0 = A + (size_t)(m0 + rowS0) * K + g0;
  const unsigned short* Ag1 = A + (size_t)(m0 + rowS1) * K + g1;
  const unsigned short* Bg0 = Bt + (size_t)(n0 + rowS0) * K + g0;
  const unsigned short* Bg1 = Bt + (size_t)(n0 + rowS1) * K + g1;
  unsigned short* lA0 = &Ash[t * 8];
  unsigned short* lA1 = &Ash[(t + 256) * 8];
  unsigned short* lB0 = &Bsh[t * 8];
  unsigned short* lB1 = &Bsh[(t + 256) * 8];

  int offA[4], offB[4];
#pragma unroll
  for (int i = 0; i < 4; ++i) {
    const int ra = wm * 64 + i * 16 + m15;
    offA[i] = ra * 32 + (quad ^ swz4(ra)) * 8;
    const int rb = wn * 64 + i * 16 + m15;
    offB[i] = rb * 32 + (quad ^ swz4(rb)) * 8;
  }

  const f32x4 vz = {0.f, 0.f, 0.f, 0.f};
  f32x4 acc[4][4];
#pragma unroll
  for (int i = 0; i < 4; ++i)
#pragma unroll
    for (int j = 0; j < 4; ++j) acc[i][j] = vz;

  const int nk = K >> 5;
  for (int kt = 0; kt < nk; ++kt) {
    const int k0 = kt * 32;
    async_copy16(Ag0 + k0, lA0);
    async_copy16(Ag1 + k0, lA1);
    async_copy16(Bg0 + k0, lB0);
    async_copy16(Bg1 + k0, lB1);
    __syncthreads();  // drains vmcnt: tile ready
    f16x8 af[4], bfr[4];
#pragma unroll
    for (int i = 0; i < 4; ++i) af[i] = *(const f16x8*)&Ash[offA[i]];
#pragma unroll
    for (int j = 0; j < 4; ++j) bfr[j] = *(const f16x8*)&Bsh[offB[j]];
#pragma unroll
    for (int i = 0; i < 4; ++i)
#pragma unroll
      for (int j = 0; j < 4; ++j)
        acc[i][j] = __builtin_amdgcn_mfma_f32_16x16x32_f16(af[i], bfr[j], acc[i][j], 0, 0, 0);
    __syncthreads();  // all reads done before next stage overwrites
  }

  // C/D layout (m89-verified): col = lane&15, row = quad*4 + reg.
#pragma unroll
  for (int i = 0; i < 4; ++i)
#pragma unroll
    for (int j = 0; j < 4; ++j)
#pragma unroll
      for (int r = 0; r < 4; ++r) {
        const int gm = m0 + wm * 64 + i * 16 + quad * 4 + r;
        const int gn = n0 + wn * 64 + j * 16 + m15;
        const float v = acc[i][j][r];
        if (OUT_MODE == 2) ((float*)Cg)[(size_t)gm * N + gn] = v;
        else               ((unsigned short*)Cg)[(size_t)gm * N + gn] = f2h(v);
      }
}

// ---------------------------------------------------------------------------
// elementwise fp32 -> fp16 (hidden pre-convert), 4 elems/thread.
// ---------------------------------------------------------------------------
__global__ __launch_bounds__(256) void cvt_f32_f16(const float* __restrict__ in,
                                                   unsigned short* __restrict__ out, int n4) {
  const int i = blockIdx.x * 256 + threadIdx.x;
  if (i >= n4) return;
  const float4 v = ((const float4*)in)[i];
  ushort4 o = {f2h(v.x), f2h(v.y), f2h(v.z), f2h(v.w)};
  ((ushort4*)out)[i] = o;
}

// ---------------------------------------------------------------------------
// transpose + convert: out_f16[C][R] = in_f32[R][C]. 64x64 tiles.
// ---------------------------------------------------------------------------
__global__ __launch_bounds__(256) void transpose_f2h(const float* __restrict__ in,
                                                     unsigned short* __restrict__ out,
                                                     int R, int C) {
  __shared__ float tile[64 * 68];  // stride 68 floats (16B-aligned rows, no pow2 conflict)
  const int r0 = blockIdx.y * 64, c0 = blockIdx.x * 64;
  const int t = threadIdx.x;
#pragma unroll
  for (int p = 0; p < 4; ++p) {
    const int idx = t + p * 256;            // [0,1024)
    const int rr = idx >> 4, cc = (idx & 15) * 4;
    *(float4*)&tile[rr * 68 + cc] = *(const float4*)&in[(size_t)(r0 + rr) * C + c0 + cc];
  }
  __syncthreads();
#pragma unroll
  for (int p = 0; p < 2; ++p) {
    const int idx = t + p * 256;            // [0,512)
    const int dr = idx >> 3, sc = (idx & 7) * 8;
    union { uint4 v; unsigned short s[8]; } o;
#pragma unroll
    for (int e = 0; e < 8; ++e) o.s[e] = f2h(tile[(sc + e) * 68 + dr]);
    *(uint4*)&out[(size_t)(c0 + dr) * R + r0 + sc] = o.v;
  }
}

// ---------------------------------------------------------------------------
// Fused per-head RMSNorm + RoPE. One block per token; wave w handles head-slot
// iter*4+w (slots 0-7 = q heads, 8-9 = k heads, 10-11 = v heads).
// Lane holds 4 contiguous dims; rope pairs (i, i+128) live in lanes l, l^32.
// ---------------------------------------------------------------------------
__global__ __launch_bounds__(256) void normrope(const unsigned short* __restrict__ qkv,  // fp16 [4096][3072]
                                                const int* __restrict__ pos,
                                                const float* __restrict__ qw,            // fp32[256]
                                                const float* __restrict__ kw,
                                                unsigned short* __restrict__ Qh,   // fp16 [B][NH][S][D]
                                                unsigned short* __restrict__ Kh,   // fp16 [B][NKV][S][D]
                                                unsigned short* __restrict__ Vh) { // fp16 [B][NKV][S][D]
  const int tok = blockIdx.x;
  const int b = tok >> 11, s = tok & 2047;
  const int t = threadIdx.x, w = t >> 6, lane = t & 63;
  const float p = (float)pos[tok];
  const int dbase = lane * 4;

  for (int it = 0; it < 3; ++it) {
    const int slot = it * 4 + w;  // wave-uniform
    const unsigned short* src = qkv + (size_t)tok * NQKV + slot * 256 + dbase;
    union { uint2 u; _Float16 h[4]; } rd;
    rd.u = *(const uint2*)src;
    float y[4];
#pragma unroll
    for (int e = 0; e < 4; ++e) y[e] = (float)rd.h[e];
    float ssq = y[0] * y[0] + y[1] * y[1] + y[2] * y[2] + y[3] * y[3];
#pragma unroll
    for (int off = 1; off < 64; off <<= 1) ssq += __shfl_xor(ssq, off);
    const float rn = rsqrtf(ssq * (1.f / 256.f) + 1e-6f);

    if (slot < 8) {
#pragma unroll
      for (int e = 0; e < 4; ++e) y[e] *= rn * qw[dbase + e];
    } else if (slot < 10) {
#pragma unroll
      for (int e = 0; e < 4; ++e) y[e] *= rn * kw[dbase + e];
    } else {
#pragma unroll
      for (int e = 0; e < 4; ++e) y[e] *= rn;
    }

    unsigned short* dst;
    if (slot < 8)       dst = Qh + ((size_t)(b * NH + slot) * SB + s) * HD + dbase;
    else if (slot < 10) dst = Kh + ((size_t)(b * NKV + slot - 8) * SB + s) * HD + dbase;
    else                dst = Vh + ((size_t)(b * NKV + slot - 10) * SB + s) * HD + dbase;

    float outv[4];
    if (slot < 10) {
      const int i0 = dbase & 127;
      const bool lo = (lane < 32);
#pragma unroll
      for (int e = 0; e < 4; ++e) {
        const float partner = __shfl_xor(y[e], 32);
        // inv_freq = 1e6^(-j/128) = exp(-j * ln(1e6)/128)
        const float invf = expf(-(float)(i0 + e) * 0.10793368f);
        const float fr = p * invf;
        const float cv = cosf(fr), sv = sinf(fr);
        outv[e] = lo ? (y[e] * cv - partner * sv) : (y[e] * cv + partner * sv);
      }
    } else {
#pragma unroll
      for (int e = 0; e < 4; ++e) outv[e] = y[e];
    }
    union { uint2 u; _Float16 h[4]; } wr;
#pragma unroll
    for (int e = 0; e < 4; ++e) wr.h[e] = (_Float16)outv[e];
    *(uint2*)dst = wr.u;
  }
}

// ---------------------------------------------------------------------------
// 16-bit transpose: out[C][R] = in[R][C], batched. 64x64 LDS tiles.
// ---------------------------------------------------------------------------
__global__ __launch_bounds__(256) void transpose_u16(const unsigned short* __restrict__ in,
                                                     unsigned short* __restrict__ out,
                                                     int R, int C, size_t ibs, size_t obs) {
  __shared__ unsigned short tile[64 * 72];  // +8 pad
  const unsigned short* ib = in + blockIdx.z * ibs;
  unsigned short* ob = out + blockIdx.z * obs;
  const int r0 = blockIdx.y * 64, c0 = blockIdx.x * 64;
  const int t = threadIdx.x;
#pragma unroll
  for (int pck = 0; pck < 2; ++pck) {
    const int c = t + pck * 256;
    const int rr = c >> 3, cc = (c & 7) * 8;
    *(uint4*)&tile[rr * 72 + cc] = *(const uint4*)&ib[(size_t)(r0 + rr) * C + c0 + cc];
  }
  __syncthreads();
#pragma unroll
  for (int pck = 0; pck < 2; ++pck) {
    const int c = t + pck * 256;
    const int dr = c >> 3, sc = (c & 7) * 8;
    union { uint4 v; unsigned short s[8]; } o;
#pragma unroll
    for (int e = 0; e < 8; ++e) o.s[e] = tile[(sc + e) * 72 + dr];
    *(uint4*)&ob[(size_t)(c0 + dr) * R + r0 + sc] = o.v;
  }
}

// ---------------------------------------------------------------------------
// Flash attention v2 (causal, no softmax scale). ONE WAVE per 16 q rows.
// No __syncthreads anywhere. K/V read directly from global (L1/L2-cached,
// GQA 4x reuse). 64-key tiles = 2 chunks of 32; fully-masked chunks skipped
// wave-uniformly. fp16 MFMA, fp32 online softmax. P transposed C->A layout
// through a private 2.3KB LDS buffer (same-wave DS ops are in-order).
// ---------------------------------------------------------------------------
__global__ __launch_bounds__(64) void flash_attn(const unsigned short* __restrict__ Qh,
                                                 const unsigned short* __restrict__ Kh,
                                                 const unsigned short* __restrict__ Vt,  // [B][NKV][D][S]
                                                 unsigned short* __restrict__ attn) {    // fp16 [B*S][NH*HD]
  __shared__ _Float16 Psh[16 * 72];  // 16 q x 64 keys (+8 pad); row stride 144B (16B-mult)
  const int qt = gridDim.x - 1 - blockIdx.x;  // big q-tiles dispatch first
  const int h = blockIdx.y, b = blockIdx.z;
  const int kv = h >> 2;  // GQA repeat(4)
  const int lane = threadIdx.x & 63;
  const int quad = lane >> 4, m15 = lane & 15;
  const int q0 = qt * 16;
  const int qlast = q0 + 15;

  // Q fragments in registers for the whole kernel: A[m=lane&15][k=quad*8+j]
  f16x8 aq[8];
  const unsigned short* qb = Qh + ((size_t)(b * NH + h) * SB + q0 + m15) * HD + quad * 8;
#pragma unroll
  for (int ks = 0; ks < 8; ++ks) aq[ks] = *(const f16x8*)(qb + ks * 32);

  const f32x4 vz = {0.f, 0.f, 0.f, 0.f};
  f32x4 o[16];
#pragma unroll
  for (int i = 0; i < 16; ++i) o[i] = vz;
  float mrow[4] = {-1e30f, -1e30f, -1e30f, -1e30f};
  float lrow[4] = {0.f, 0.f, 0.f, 0.f};

  const unsigned short* Kb = Kh + (size_t)(b * NKV + kv) * SB * HD;
  const unsigned short* Vb = Vt + (size_t)(b * NKV + kv) * HD * SB;

  const int nkt = (q0 + 16 + 63) >> 6;  // 64-key tiles up to row q0+15
  for (int kt = 0; kt < nkt; ++kt) {
    const int k0 = kt * 64;
    const int nchunk = (k0 + 32 <= qlast) ? 2 : 1;  // wave-uniform

    // ---- scores S[16 q][nchunk*32 keys] ----
    f32x4 sv[4];
#pragma unroll
    for (int g = 0; g < 4; ++g) sv[g] = vz;
    for (int c = 0; c < nchunk; ++c) {
      const unsigned short* kbase = Kb + (size_t)(k0 + c * 32 + m15) * HD + quad * 8;
#pragma unroll
      for (int ks = 0; ks < 8; ++ks) {
        const f16x8 bk0 = *(const f16x8*)(kbase + ks * 32);
        const f16x8 bk1 = *(const f16x8*)(kbase + 16 * HD + ks * 32);
        sv[2 * c]     = __builtin_amdgcn_mfma_f32_16x16x32_f16(aq[ks], bk0, sv[2 * c], 0, 0, 0);
        sv[2 * c + 1] = __builtin_amdgcn_mfma_f32_16x16x32_f16(aq[ks], bk1, sv[2 * c + 1], 0, 0, 0);
      }
    }

    // ---- online softmax over up to 64 cols ----
#pragma unroll
    for (int r = 0; r < 4; ++r) {
      const int q = q0 + quad * 4 + r;
      float s[4];
#pragma unroll
      for (int g = 0; g < 4; ++g) {
        const bool live = (g < 2 * nchunk) && ((k0 + g * 16 + m15) <= q);
        s[g] = live ? sv[g][r] : -3.0e38f;
      }
      float tm = fmaxf(fmaxf(s[0], s[1]), fmaxf(s[2], s[3]));
#pragma unroll
      for (int off = 1; off < 16; off <<= 1) tm = fmaxf(tm, __shfl_xor(tm, off));
      const float mnew = fmaxf(mrow[r], tm);
      const float alpha = __expf(mrow[r] - mnew);
      float p[4], rs = 0.f;
#pragma unroll
      for (int g = 0; g < 4; ++g) { p[g] = __expf(s[g] - mnew); rs += p[g]; }
#pragma unroll
      for (int off = 1; off < 16; off <<= 1) rs += __shfl_xor(rs, off);
      lrow[r] = lrow[r] * alpha + rs;
      mrow[r] = mnew;
#pragma unroll
      for (int dbi = 0; dbi < 16; ++dbi) o[dbi][r] *= alpha;
      // P -> LDS (C-layout rows)
#pragma unroll
      for (int g = 0; g < 4; ++g)
        if (g < 2 * nchunk) Psh[(quad * 4 + r) * 72 + g * 16 + m15] = (_Float16)p[g];
    }

    // ---- PV: o += P[16 x 32c] * V^T chunks (same-wave LDS is in-order) ----
    asm volatile("" ::: "memory");
    for (int c = 0; c < nchunk; ++c) {
      const f16x8 ap = *(const f16x8*)&Psh[m15 * 72 + c * 32 + quad * 8];
      const unsigned short* vbase = Vb + (size_t)m15 * SB + k0 + c * 32 + quad * 8;
#pragma unroll
      for (int dbi = 0; dbi < 16; ++dbi) {
        const f16x8 bv = *(const f16x8*)(vbase + (size_t)dbi * 16 * SB);
        o[dbi] = __builtin_amdgcn_mfma_f32_16x16x32_f16(ap, bv, o[dbi], 0, 0, 0);
      }
    }
  }

  float inv[4];
#pragma unroll
  for (int r = 0; r < 4; ++r) inv[r] = 1.0f / lrow[r];
#pragma unroll
  for (int dbi = 0; dbi < 16; ++dbi)
#pragma unroll
    for (int r = 0; r < 4; ++r) {
      const int q = q0 + quad * 4 + r;
      const int col = h * HD + dbi * 16 + m15;
      attn[(size_t)(b * SB + q) * (NH * HD) + col] = f2h(o[dbi][r] * inv[r]);
    }
}

// ---------------------------------------------------------------------------
// workspace layout (bytes), total 60 MiB with lifetime-based reuse:
//  [0,16M)    hidden_f16 (dead after gemm1)      -> Qh (normrope..flash_attn)
//  [16M,28M)  wqkvT f16  (dead after gemm1)      -> Kh | Vh | Vt
//  [28M,36M)  woT f16    (live to gemm2)
//  [36M,60M)  qkv f16    (dead after normrope)   -> attn f16
// ---------------------------------------------------------------------------
static constexpr size_t OFF_HB   = 0;
static constexpr size_t OFF_QH   = 0;                      // 16,777,216
static constexpr size_t OFF_W1T  = 16777216;               // 12,582,912
static constexpr size_t OFF_KH   = 16777216;               //  4,194,304
static constexpr size_t OFF_VH   = 20971520;               //  4,194,304
static constexpr size_t OFF_VT   = 25165824;               //  4,194,304
static constexpr size_t OFF_WOT  = 29360128;               //  8,388,608
static constexpr size_t OFF_QKV  = 37748736;               // 25,165,824 -> 62,914,560
static constexpr size_t OFF_ATTN = OFF_QKV;                // 16,777,216 (reuse)

extern "C" void kernel_launch(void* const* d_in, const int* in_sizes, int n_in,
                              void* d_out, int out_size, void* d_ws, size_t ws_size,
                              hipStream_t stream) {
  const float* hidden    = (const float*)d_in[0];  // fp32 (2,2048,2048)
  const int*   positions = (const int*)d_in[1];    // int32 (2,2048)
  const float* w_qkv     = (const float*)d_in[2];  // fp32 (2048,3072)
  const float* w_o       = (const float*)d_in[3];  // fp32 (2048,2048)
  const float* qw        = (const float*)d_in[4];  // fp32 (256)
  const float* kw        = (const float*)d_in[5];  // fp32 (256)
  float* out = (float*)d_out;                      // fp32 (2,2048,2048)
  char* ws = (char*)d_ws;

  unsigned short* hb    = (unsigned short*)(ws + OFF_HB);
  unsigned short* wqkvT = (unsigned short*)(ws + OFF_W1T);
  unsigned short* woT   = (unsigned short*)(ws + OFF_WOT);
  unsigned short* qkvb  = (unsigned short*)(ws + OFF_QKV);
  unsigned short* attnb = (unsigned short*)(ws + OFF_ATTN);
  unsigned short* Qhb   = (unsigned short*)(ws + OFF_QH);
  unsigned short* Khb   = (unsigned short*)(ws + OFF_KH);
  unsigned short* Vhb   = (unsigned short*)(ws + OFF_VH);
  unsigned short* Vtb   = (unsigned short*)(ws + OFF_VT);

  // hidden fp32 -> fp16 [M][K]
  cvt_f32_f16<<<dim3((MTOK * HID / 4 + 255) / 256), 256, 0, stream>>>(hidden, hb, MTOK * HID / 4);
  // weights fp32 [K][N] -> fp16 [N][K]
  transpose_f2h<<<dim3(NQKV / 64, HID / 64), 256, 0, stream>>>(w_qkv, wqkvT, HID, NQKV);
  transpose_f2h<<<dim3(HID / 64, HID / 64), 256, 0, stream>>>(w_o, woT, HID, HID);

  // qkv = hidden @ w_qkv  (fp16 out)
  gemm_bt<0><<<dim3(NQKV / 128, MTOK / 128), 256, 0, stream>>>(hb, wqkvT, qkvb, MTOK, NQKV, HID);

  normrope<<<dim3(MTOK), 256, 0, stream>>>(qkvb, positions, qw, kw, Qhb, Khb, Vhb);

  // V -> [B][NKV][D][S] for PV b-frags
  transpose_u16<<<dim3(HD / 64, SB / 64, BB * NKV), 256, 0, stream>>>(Vhb, Vtb, SB, HD,
                                                                     (size_t)SB * HD, (size_t)SB * HD);

  flash_attn<<<dim3(SB / 16, NH, BB), 64, 0, stream>>>(Qhb, Khb, Vtb, attnb);

  // out = attn @ w_o (fp32 out)
  gemm_bt<2><<<dim3(HID / 128, MTOK / 128), 256, 0, stream>>>(attnb, woT, out, MTOK, HID, HID);
}

// Round 6
// 465.340 us; speedup vs baseline: 1.6281x; 1.6281x over previous
//
#include <hip/hip_runtime.h>

// Gemma3nAttention: hidden(2,2048,2048) fp32 -> qkv gemm -> per-head rmsnorm ->
// rope -> GQA causal attention (no softmax scale!) -> out-proj -> (2,2048,2048) fp32.
// R5: flash v3 = R3 structure (4 waves/64 q-rows, LDS-staged K/V — measured 188us;
// R4's single-wave direct-global version serialized on vmcnt and hit 492us) with:
//   (1) 64-key tiles: half the barriers / softmax rounds / o-rescales per key,
//   (2) global_load_lds width-16 staging, flat LDS + fetch-side XOR swizzle,
//   (3) causal mask applied only in the final K-tile (wave-uniform branch).

#define HID  2048
#define NH   8
#define NKV  2
#define HD   256
#define SB   2048
#define BB   2
#define MTOK (BB * SB)                 // 4096
#define NQKV ((NH + 2 * NKV) * HD)     // 3072

typedef _Float16  f16x8 __attribute__((ext_vector_type(8)));
typedef float     f32x4 __attribute__((ext_vector_type(4)));

__device__ __forceinline__ unsigned short f2h(float f) {
  _Float16 h = (_Float16)f;
  return __builtin_bit_cast(unsigned short, h);
}

// async global->LDS, 16B per lane (m97/m104): LDS dest = wave-uniform base +
// lane*16; all call sites satisfy that by construction (thread t -> byte 16t).
__device__ __forceinline__ void async_copy16(const unsigned short* g, unsigned short* l) {
  __builtin_amdgcn_global_load_lds(
      (const __attribute__((address_space(1))) unsigned int*)g,
      (__attribute__((address_space(3))) unsigned int*)l, 16, 0, 0);
}

__device__ __forceinline__ int swz4(int r) { return (r + (r >> 2)) & 3; }

// ---------------------------------------------------------------------------
// GEMM: C[M][N] = A[M][K] * Bt[N][K]^T, fp16 in, fp32 accum.
// OUT_MODE: 0 = fp16(u16), 2 = fp32(float).
// 128x128 tile, BK=32, 4 waves of 64x64 (4x4 mfma_f32_16x16x32_f16). m97 shape.
// ---------------------------------------------------------------------------
template <int OUT_MODE>
__global__ __launch_bounds__(256) void gemm_bt(const unsigned short* __restrict__ A,
                                               const unsigned short* __restrict__ Bt,
                                               void* __restrict__ Cg,
                                               int M, int N, int K) {
  __shared__ unsigned short Ash[128 * 32];
  __shared__ unsigned short Bsh[128 * 32];
  const int t = threadIdx.x;
  const int lane = t & 63, w = t >> 6;
  const int quad = lane >> 4, m15 = lane & 15;
  const int wm = w >> 1, wn = w & 1;
  const int m0 = blockIdx.y * 128, n0 = blockIdx.x * 128;

  const int rowS0 = t >> 2, rowS1 = rowS0 + 64;
  const int slot = t & 3;
  const int g0 = (slot ^ swz4(rowS0)) * 8;
  const int g1 = (slot ^ swz4(rowS1)) * 8;
  const unsigned short* Ag0 = A + (size_t)(m0 + rowS0) * K + g0;
  const unsigned short* Ag1 = A + (size_t)(m0 + rowS1) * K + g1;
  const unsigned short* Bg0 = Bt + (size_t)(n0 + rowS0) * K + g0;
  const unsigned short* Bg1 = Bt + (size_t)(n0 + rowS1) * K + g1;
  unsigned short* lA0 = &Ash[t * 8];
  unsigned short* lA1 = &Ash[(t + 256) * 8];
  unsigned short* lB0 = &Bsh[t * 8];
  unsigned short* lB1 = &Bsh[(t + 256) * 8];

  int offA[4], offB[4];
#pragma unroll
  for (int i = 0; i < 4; ++i) {
    const int ra = wm * 64 + i * 16 + m15;
    offA[i] = ra * 32 + (quad ^ swz4(ra)) * 8;
    const int rb = wn * 64 + i * 16 + m15;
    offB[i] = rb * 32 + (quad ^ swz4(rb)) * 8;
  }

  const f32x4 vz = {0.f, 0.f, 0.f, 0.f};
  f32x4 acc[4][4];
#pragma unroll
  for (int i = 0; i < 4; ++i)
#pragma unroll
    for (int j = 0; j < 4; ++j) acc[i][j] = vz;

  const int nk = K >> 5;
  for (int kt = 0; kt < nk; ++kt) {
    const int k0 = kt * 32;
    async_copy16(Ag0 + k0, lA0);
    async_copy16(Ag1 + k0, lA1);
    async_copy16(Bg0 + k0, lB0);
    async_copy16(Bg1 + k0, lB1);
    __syncthreads();  // drains vmcnt: tile ready
    f16x8 af[4], bfr[4];
#pragma unroll
    for (int i = 0; i < 4; ++i) af[i] = *(const f16x8*)&Ash[offA[i]];
#pragma unroll
    for (int j = 0; j < 4; ++j) bfr[j] = *(const f16x8*)&Bsh[offB[j]];
#pragma unroll
    for (int i = 0; i < 4; ++i)
#pragma unroll
      for (int j = 0; j < 4; ++j)
        acc[i][j] = __builtin_amdgcn_mfma_f32_16x16x32_f16(af[i], bfr[j], acc[i][j], 0, 0, 0);
    __syncthreads();  // all reads done before next stage overwrites
  }

  // C/D layout (m89-verified): col = lane&15, row = quad*4 + reg.
#pragma unroll
  for (int i = 0; i < 4; ++i)
#pragma unroll
    for (int j = 0; j < 4; ++j)
#pragma unroll
      for (int r = 0; r < 4; ++r) {
        const int gm = m0 + wm * 64 + i * 16 + quad * 4 + r;
        const int gn = n0 + wn * 64 + j * 16 + m15;
        const float v = acc[i][j][r];
        if (OUT_MODE == 2) ((float*)Cg)[(size_t)gm * N + gn] = v;
        else               ((unsigned short*)Cg)[(size_t)gm * N + gn] = f2h(v);
      }
}

// ---------------------------------------------------------------------------
// elementwise fp32 -> fp16 (hidden pre-convert), 4 elems/thread.
// ---------------------------------------------------------------------------
__global__ __launch_bounds__(256) void cvt_f32_f16(const float* __restrict__ in,
                                                   unsigned short* __restrict__ out, int n4) {
  const int i = blockIdx.x * 256 + threadIdx.x;
  if (i >= n4) return;
  const float4 v = ((const float4*)in)[i];
  ushort4 o = {f2h(v.x), f2h(v.y), f2h(v.z), f2h(v.w)};
  ((ushort4*)out)[i] = o;
}

// ---------------------------------------------------------------------------
// transpose + convert: out_f16[C][R] = in_f32[R][C]. 64x64 tiles.
// ---------------------------------------------------------------------------
__global__ __launch_bounds__(256) void transpose_f2h(const float* __restrict__ in,
                                                     unsigned short* __restrict__ out,
                                                     int R, int C) {
  __shared__ float tile[64 * 68];  // stride 68 floats (16B-aligned rows, no pow2 conflict)
  const int r0 = blockIdx.y * 64, c0 = blockIdx.x * 64;
  const int t = threadIdx.x;
#pragma unroll
  for (int p = 0; p < 4; ++p) {
    const int idx = t + p * 256;            // [0,1024)
    const int rr = idx >> 4, cc = (idx & 15) * 4;
    *(float4*)&tile[rr * 68 + cc] = *(const float4*)&in[(size_t)(r0 + rr) * C + c0 + cc];
  }
  __syncthreads();
#pragma unroll
  for (int p = 0; p < 2; ++p) {
    const int idx = t + p * 256;            // [0,512)
    const int dr = idx >> 3, sc = (idx & 7) * 8;
    union { uint4 v; unsigned short s[8]; } o;
#pragma unroll
    for (int e = 0; e < 8; ++e) o.s[e] = f2h(tile[(sc + e) * 68 + dr]);
    *(uint4*)&out[(size_t)(c0 + dr) * R + r0 + sc] = o.v;
  }
}

// ---------------------------------------------------------------------------
// Fused per-head RMSNorm + RoPE. One block per token; wave w handles head-slot
// iter*4+w (slots 0-7 = q heads, 8-9 = k heads, 10-11 = v heads).
// ---------------------------------------------------------------------------
__global__ __launch_bounds__(256) void normrope(const unsigned short* __restrict__ qkv,  // fp16 [4096][3072]
                                                const int* __restrict__ pos,
                                                const float* __restrict__ qw,            // fp32[256]
                                                const float* __restrict__ kw,
                                                unsigned short* __restrict__ Qh,   // fp16 [B][NH][S][D]
                                                unsigned short* __restrict__ Kh,   // fp16 [B][NKV][S][D]
                                                unsigned short* __restrict__ Vh) { // fp16 [B][NKV][S][D]
  const int tok = blockIdx.x;
  const int b = tok >> 11, s = tok & 2047;
  const int t = threadIdx.x, w = t >> 6, lane = t & 63;
  const float p = (float)pos[tok];
  const int dbase = lane * 4;

  for (int it = 0; it < 3; ++it) {
    const int slot = it * 4 + w;  // wave-uniform
    const unsigned short* src = qkv + (size_t)tok * NQKV + slot * 256 + dbase;
    union { uint2 u; _Float16 h[4]; } rd;
    rd.u = *(const uint2*)src;
    float y[4];
#pragma unroll
    for (int e = 0; e < 4; ++e) y[e] = (float)rd.h[e];
    float ssq = y[0] * y[0] + y[1] * y[1] + y[2] * y[2] + y[3] * y[3];
#pragma unroll
    for (int off = 1; off < 64; off <<= 1) ssq += __shfl_xor(ssq, off);
    const float rn = rsqrtf(ssq * (1.f / 256.f) + 1e-6f);

    if (slot < 8) {
#pragma unroll
      for (int e = 0; e < 4; ++e) y[e] *= rn * qw[dbase + e];
    } else if (slot < 10) {
#pragma unroll
      for (int e = 0; e < 4; ++e) y[e] *= rn * kw[dbase + e];
    } else {
#pragma unroll
      for (int e = 0; e < 4; ++e) y[e] *= rn;
    }

    unsigned short* dst;
    if (slot < 8)       dst = Qh + ((size_t)(b * NH + slot) * SB + s) * HD + dbase;
    else if (slot < 10) dst = Kh + ((size_t)(b * NKV + slot - 8) * SB + s) * HD + dbase;
    else                dst = Vh + ((size_t)(b * NKV + slot - 10) * SB + s) * HD + dbase;

    float outv[4];
    if (slot < 10) {
      const int i0 = dbase & 127;
      const bool lo = (lane < 32);
#pragma unroll
      for (int e = 0; e < 4; ++e) {
        const float partner = __shfl_xor(y[e], 32);
        const float invf = expf(-(float)(i0 + e) * 0.10793368f);  // 1e6^(-j/128)
        const float fr = p * invf;
        const float cv = cosf(fr), sv = sinf(fr);
        outv[e] = lo ? (y[e] * cv - partner * sv) : (y[e] * cv + partner * sv);
      }
    } else {
#pragma unroll
      for (int e = 0; e < 4; ++e) outv[e] = y[e];
    }
    union { uint2 u; _Float16 h[4]; } wr;
#pragma unroll
    for (int e = 0; e < 4; ++e) wr.h[e] = (_Float16)outv[e];
    *(uint2*)dst = wr.u;
  }
}

// ---------------------------------------------------------------------------
// 16-bit transpose: out[C][R] = in[R][C], batched. 64x64 LDS tiles.
// ---------------------------------------------------------------------------
__global__ __launch_bounds__(256) void transpose_u16(const unsigned short* __restrict__ in,
                                                     unsigned short* __restrict__ out,
                                                     int R, int C, size_t ibs, size_t obs) {
  __shared__ unsigned short tile[64 * 72];  // +8 pad
  const unsigned short* ib = in + blockIdx.z * ibs;
  unsigned short* ob = out + blockIdx.z * obs;
  const int r0 = blockIdx.y * 64, c0 = blockIdx.x * 64;
  const int t = threadIdx.x;
#pragma unroll
  for (int pck = 0; pck < 2; ++pck) {
    const int c = t + pck * 256;
    const int rr = c >> 3, cc = (c & 7) * 8;
    *(uint4*)&tile[rr * 72 + cc] = *(const uint4*)&ib[(size_t)(r0 + rr) * C + c0 + cc];
  }
  __syncthreads();
#pragma unroll
  for (int pck = 0; pck < 2; ++pck) {
    const int c = t + pck * 256;
    const int dr = c >> 3, sc = (c & 7) * 8;
    union { uint4 v; unsigned short s[8]; } o;
#pragma unroll
    for (int e = 0; e < 8; ++e) o.s[e] = tile[(sc + e) * 72 + dr];
    *(uint4*)&ob[(size_t)(c0 + dr) * R + r0 + sc] = o.v;
  }
}

// ---------------------------------------------------------------------------
// Flash attention v3 (causal, no softmax scale). Block = 64 q rows (4 waves),
// 64-key tiles staged K+V into LDS via global_load_lds w16 (flat layout,
// fetch-side XOR swizzle; read side XORs the same pattern). fp16 MFMA, fp32
// online softmax; mask only in the final tile; P C->A via per-wave LDS.
// LDS: Ksh 32KB + Vsh 32KB + Psh 9.2KB = 73.2KB -> 2 blocks/CU.
// ---------------------------------------------------------------------------
__global__ __launch_bounds__(256) void flash_attn(const unsigned short* __restrict__ Qh,
                                                  const unsigned short* __restrict__ Kh,
                                                  const unsigned short* __restrict__ Vt,  // [B][NKV][D][S]
                                                  unsigned short* __restrict__ attn) {    // fp16 [B*S][NH*HD]
  __shared__ unsigned short Ksh[64 * 256];   // [key][d] flat, swizzled 16B chunks
  __shared__ unsigned short Vsh[256 * 64];   // [d][key] flat, swizzled 16B chunks
  __shared__ _Float16 Psh[4][16 * 72];       // per-wave 16 q x 64 keys (+8 pad)
  const int qt = gridDim.x - 1 - blockIdx.x;  // big q-tiles dispatch first
  const int h = blockIdx.y, b = blockIdx.z;
  const int kv = h >> 2;  // GQA repeat(4)
  const int t = threadIdx.x, w = t >> 6, lane = t & 63;
  const int quad = lane >> 4, m15 = lane & 15;
  const int q0 = qt * 64, qw0 = q0 + w * 16;

  // Q fragments in registers for the whole kernel: A[m=lane&15][k=quad*8+j]
  f16x8 aq[8];
  const unsigned short* qb = Qh + ((size_t)(b * NH + h) * SB + qw0 + m15) * HD + quad * 8;
#pragma unroll
  for (int ks = 0; ks < 8; ++ks) aq[ks] = *(const f16x8*)(qb + ks * 32);

  const f32x4 vz = {0.f, 0.f, 0.f, 0.f};
  f32x4 o[16];
#pragma unroll
  for (int i = 0; i < 16; ++i) o[i] = vz;
  float mrow[4] = {-1e30f, -1e30f, -1e30f, -1e30f};
  float lrow[4] = {0.f, 0.f, 0.f, 0.f};

  const unsigned short* Kb = Kh + (size_t)(b * NKV + kv) * SB * HD;
  const unsigned short* Vb = Vt + (size_t)(b * NKV + kv) * HD * SB;

  // staging geometry (per thread, per 4KB shot):
  //  K: LDS byte 16t+4096*shot -> row = t/32 + 8*shot (key), chunk = t&31 (16B col)
  //  V: LDS byte 16t+4096*shot -> row = t/8  + 32*shot (d),  chunk = t&7
  const int krow = t >> 5, kchunk = t & 31;
  const int vrow = t >> 3, vchunk = t & 7;

  const int nkt = (q0 + 64) >> 6;
  for (int kt = 0; kt < nkt; ++kt) {
    const int k0 = kt * 64;
    __syncthreads();  // prev-iter LDS reads complete before overwrite
#pragma unroll
    for (int shot = 0; shot < 8; ++shot) {
      const int r = krow + 8 * shot;
      async_copy16(Kb + (size_t)(k0 + r) * HD + ((kchunk ^ (r & 7)) * 8),
                   &Ksh[(size_t)(4096 / 2) * shot + t * 8]);
    }
#pragma unroll
    for (int shot = 0; shot < 8; ++shot) {
      const int d = vrow + 32 * shot;
      async_copy16(Vb + (size_t)d * SB + k0 + ((vchunk ^ (d & 7)) * 8),
                   &Vsh[(size_t)(4096 / 2) * shot + t * 8]);
    }
    __syncthreads();  // drains vmcnt: K/V tile ready

    // ---- scores S[16 q][64 keys]: 4 groups of 16 keys ----
    f32x4 sv[4];
#pragma unroll
    for (int g = 0; g < 4; ++g) sv[g] = vz;
#pragma unroll
    for (int g = 0; g < 4; ++g) {
      const int key = g * 16 + m15;
      const unsigned short* kr = &Ksh[key * 256];
      const int sw = (key & 7);
#pragma unroll
      for (int ks = 0; ks < 8; ++ks) {
        const f16x8 bk = *(const f16x8*)&kr[((4 * ks + quad) ^ sw) * 8];
        sv[g] = __builtin_amdgcn_mfma_f32_16x16x32_f16(aq[ks], bk, sv[g], 0, 0, 0);
      }
    }

    // ---- online softmax over 64 cols ----
    const bool last = (kt == nkt - 1);  // wave-uniform
#pragma unroll
    for (int r = 0; r < 4; ++r) {
      const int q = qw0 + quad * 4 + r;
      float s[4];
#pragma unroll
      for (int g = 0; g < 4; ++g) {
        s[g] = sv[g][r];
        if (last && (k0 + g * 16 + m15) > q) s[g] = -3.0e38f;
      }
      float tm = fmaxf(fmaxf(s[0], s[1]), fmaxf(s[2], s[3]));
#pragma unroll
      for (int off = 1; off < 16; off <<= 1) tm = fmaxf(tm, __shfl_xor(tm, off));
      const float mnew = fmaxf(mrow[r], tm);
      const float alpha = __expf(mrow[r] - mnew);
      float p[4], rs = 0.f;
#pragma unroll
      for (int g = 0; g < 4; ++g) { p[g] = __expf(s[g] - mnew); rs += p[g]; }
#pragma unroll
      for (int off = 1; off < 16; off <<= 1) rs += __shfl_xor(rs, off);
      lrow[r] = lrow[r] * alpha + rs;
      mrow[r] = mnew;
#pragma unroll
      for (int dbi = 0; dbi < 16; ++dbi) o[dbi][r] *= alpha;
      _Float16* pr = &Psh[w][(quad * 4 + r) * 72];
#pragma unroll
      for (int g = 0; g < 4; ++g) pr[g * 16 + m15] = (_Float16)p[g];
    }

    // ---- PV: o += P[16x64] * Vsh (same-wave LDS in-order; no barrier) ----
    asm volatile("" ::: "memory");
#pragma unroll
    for (int c = 0; c < 2; ++c) {
      const f16x8 ap = *(const f16x8*)&Psh[w][m15 * 72 + c * 32 + quad * 8];
#pragma unroll
      for (int dbi = 0; dbi < 16; ++dbi) {
        const int d = dbi * 16 + m15;
        const f16x8 bv = *(const f16x8*)&Vsh[d * 64 + (((4 * c + quad) ^ (d & 7)) * 8)];
        o[dbi] = __builtin_amdgcn_mfma_f32_16x16x32_f16(ap, bv, o[dbi], 0, 0, 0);
      }
    }
  }

  float inv[4];
#pragma unroll
  for (int r = 0; r < 4; ++r) inv[r] = 1.0f / lrow[r];
#pragma unroll
  for (int dbi = 0; dbi < 16; ++dbi)
#pragma unroll
    for (int r = 0; r < 4; ++r) {
      const int q = qw0 + quad * 4 + r;
      const int col = h * HD + dbi * 16 + m15;
      attn[(size_t)(b * SB + q) * (NH * HD) + col] = f2h(o[dbi][r] * inv[r]);
    }
}

// ---------------------------------------------------------------------------
// workspace layout (bytes), total 60 MiB with lifetime-based reuse:
//  [0,16M)    hidden_f16 (dead after gemm1)      -> Qh (normrope..flash_attn)
//  [16M,28M)  wqkvT f16  (dead after gemm1)      -> Kh | Vh | Vt
//  [28M,36M)  woT f16    (live to gemm2)
//  [36M,60M)  qkv f16    (dead after normrope)   -> attn f16
// ---------------------------------------------------------------------------
static constexpr size_t OFF_HB   = 0;
static constexpr size_t OFF_QH   = 0;                      // 16,777,216
static constexpr size_t OFF_W1T  = 16777216;               // 12,582,912
static constexpr size_t OFF_KH   = 16777216;               //  4,194,304
static constexpr size_t OFF_VH   = 20971520;               //  4,194,304
static constexpr size_t OFF_VT   = 25165824;               //  4,194,304
static constexpr size_t OFF_WOT  = 29360128;               //  8,388,608
static constexpr size_t OFF_QKV  = 37748736;               // 25,165,824 -> 62,914,560
static constexpr size_t OFF_ATTN = OFF_QKV;                // 16,777,216 (reuse)

extern "C" void kernel_launch(void* const* d_in, const int* in_sizes, int n_in,
                              void* d_out, int out_size, void* d_ws, size_t ws_size,
                              hipStream_t stream) {
  const float* hidden    = (const float*)d_in[0];  // fp32 (2,2048,2048)
  const int*   positions = (const int*)d_in[1];    // int32 (2,2048)
  const float* w_qkv     = (const float*)d_in[2];  // fp32 (2048,3072)
  const float* w_o       = (const float*)d_in[3];  // fp32 (2048,2048)
  const float* qw        = (const float*)d_in[4];  // fp32 (256)
  const float* kw        = (const float*)d_in[5];  // fp32 (256)
  float* out = (float*)d_out;                      // fp32 (2,2048,2048)
  char* ws = (char*)d_ws;

  unsigned short* hb    = (unsigned short*)(ws + OFF_HB);
  unsigned short* wqkvT = (unsigned short*)(ws + OFF_W1T);
  unsigned short* woT   = (unsigned short*)(ws + OFF_WOT);
  unsigned short* qkvb  = (unsigned short*)(ws + OFF_QKV);
  unsigned short* attnb = (unsigned short*)(ws + OFF_ATTN);
  unsigned short* Qhb   = (unsigned short*)(ws + OFF_QH);
  unsigned short* Khb   = (unsigned short*)(ws + OFF_KH);
  unsigned short* Vhb   = (unsigned short*)(ws + OFF_VH);
  unsigned short* Vtb   = (unsigned short*)(ws + OFF_VT);

  // hidden fp32 -> fp16 [M][K]
  cvt_f32_f16<<<dim3((MTOK * HID / 4 + 255) / 256), 256, 0, stream>>>(hidden, hb, MTOK * HID / 4);
  // weights fp32 [K][N] -> fp16 [N][K]
  transpose_f2h<<<dim3(NQKV / 64, HID / 64), 256, 0, stream>>>(w_qkv, wqkvT, HID, NQKV);
  transpose_f2h<<<dim3(HID / 64, HID / 64), 256, 0, stream>>>(w_o, woT, HID, HID);

  // qkv = hidden @ w_qkv  (fp16 out)
  gemm_bt<0><<<dim3(NQKV / 128, MTOK / 128), 256, 0, stream>>>(hb, wqkvT, qkvb, MTOK, NQKV, HID);

  normrope<<<dim3(MTOK), 256, 0, stream>>>(qkvb, positions, qw, kw, Qhb, Khb, Vhb);

  // V -> [B][NKV][D][S] for PV b-frags
  transpose_u16<<<dim3(HD / 64, SB / 64, BB * NKV), 256, 0, stream>>>(Vhb, Vtb, SB, HD,
                                                                     (size_t)SB * HD, (size_t)SB * HD);

  flash_attn<<<dim3(SB / 64, NH, BB), 256, 0, stream>>>(Qhb, Khb, Vtb, attnb);

  // out = attn @ w_o (fp32 out)
  gemm_bt<2><<<dim3(HID / 128, MTOK / 128), 256, 0, stream>>>(attnb, woT, out, MTOK, HID, HID);
}

// Round 7
// 382.680 us; speedup vs baseline: 1.9798x; 1.2160x over previous
//
#include <hip/hip_runtime.h>

// Gemma3nAttention: hidden(2,2048,2048) fp32 -> qkv gemm -> per-head rmsnorm ->
// rope -> GQA causal attention (no softmax scale!) -> out-proj -> (2,2048,2048) fp32.
// R6: flash v4. Evidence from R3/R4/R5: no pipe >15% busy -> latency+tail bound.
//  (1) causal balance: block = q-tile pair (qa, 31-qa) processed sequentially
//      -> uniform 33 tiles/block, 256 blocks = 1/CU exactly, no tail.
//  (2) K/V double-buffer (LDS 137KB, 1 block/CU): stage(t+1) issued before
//      compute(t); the compiler's vmcnt(0)-before-barrier then drains AFTER
//      ~1.6k cycles of compute -> staging latency off the critical path.
//      One barrier per tile (was 2).

#define HID  2048
#define NH   8
#define NKV  2
#define HD   256
#define SB   2048
#define BB   2
#define MTOK (BB * SB)                 // 4096
#define NQKV ((NH + 2 * NKV) * HD)     // 3072

typedef _Float16  f16x8 __attribute__((ext_vector_type(8)));
typedef float     f32x4 __attribute__((ext_vector_type(4)));

__device__ __forceinline__ unsigned short f2h(float f) {
  _Float16 h = (_Float16)f;
  return __builtin_bit_cast(unsigned short, h);
}

// async global->LDS, 16B per lane (m97/m104): LDS dest = wave-uniform base +
// lane*16; all call sites satisfy that by construction (thread t -> byte 16t).
__device__ __forceinline__ void async_copy16(const unsigned short* g, unsigned short* l) {
  __builtin_amdgcn_global_load_lds(
      (const __attribute__((address_space(1))) unsigned int*)g,
      (__attribute__((address_space(3))) unsigned int*)l, 16, 0, 0);
}

__device__ __forceinline__ int swz4(int r) { return (r + (r >> 2)) & 3; }

// ---------------------------------------------------------------------------
// GEMM: C[M][N] = A[M][K] * Bt[N][K]^T, fp16 in, fp32 accum.
// OUT_MODE: 0 = fp16(u16), 2 = fp32(float).
// 128x128 tile, BK=32, 4 waves of 64x64 (4x4 mfma_f32_16x16x32_f16). m97 shape.
// ---------------------------------------------------------------------------
template <int OUT_MODE>
__global__ __launch_bounds__(256) void gemm_bt(const unsigned short* __restrict__ A,
                                               const unsigned short* __restrict__ Bt,
                                               void* __restrict__ Cg,
                                               int M, int N, int K) {
  __shared__ unsigned short Ash[128 * 32];
  __shared__ unsigned short Bsh[128 * 32];
  const int t = threadIdx.x;
  const int lane = t & 63, w = t >> 6;
  const int quad = lane >> 4, m15 = lane & 15;
  const int wm = w >> 1, wn = w & 1;
  const int m0 = blockIdx.y * 128, n0 = blockIdx.x * 128;

  const int rowS0 = t >> 2, rowS1 = rowS0 + 64;
  const int slot = t & 3;
  const int g0 = (slot ^ swz4(rowS0)) * 8;
  const int g1 = (slot ^ swz4(rowS1)) * 8;
  const unsigned short* Ag0 = A + (size_t)(m0 + rowS0) * K + g0;
  const unsigned short* Ag1 = A + (size_t)(m0 + rowS1) * K + g1;
  const unsigned short* Bg0 = Bt + (size_t)(n0 + rowS0) * K + g0;
  const unsigned short* Bg1 = Bt + (size_t)(n0 + rowS1) * K + g1;
  unsigned short* lA0 = &Ash[t * 8];
  unsigned short* lA1 = &Ash[(t + 256) * 8];
  unsigned short* lB0 = &Bsh[t * 8];
  unsigned short* lB1 = &Bsh[(t + 256) * 8];

  int offA[4], offB[4];
#pragma unroll
  for (int i = 0; i < 4; ++i) {
    const int ra = wm * 64 + i * 16 + m15;
    offA[i] = ra * 32 + (quad ^ swz4(ra)) * 8;
    const int rb = wn * 64 + i * 16 + m15;
    offB[i] = rb * 32 + (quad ^ swz4(rb)) * 8;
  }

  const f32x4 vz = {0.f, 0.f, 0.f, 0.f};
  f32x4 acc[4][4];
#pragma unroll
  for (int i = 0; i < 4; ++i)
#pragma unroll
    for (int j = 0; j < 4; ++j) acc[i][j] = vz;

  const int nk = K >> 5;
  for (int kt = 0; kt < nk; ++kt) {
    const int k0 = kt * 32;
    async_copy16(Ag0 + k0, lA0);
    async_copy16(Ag1 + k0, lA1);
    async_copy16(Bg0 + k0, lB0);
    async_copy16(Bg1 + k0, lB1);
    __syncthreads();  // drains vmcnt: tile ready
    f16x8 af[4], bfr[4];
#pragma unroll
    for (int i = 0; i < 4; ++i) af[i] = *(const f16x8*)&Ash[offA[i]];
#pragma unroll
    for (int j = 0; j < 4; ++j) bfr[j] = *(const f16x8*)&Bsh[offB[j]];
#pragma unroll
    for (int i = 0; i < 4; ++i)
#pragma unroll
      for (int j = 0; j < 4; ++j)
        acc[i][j] = __builtin_amdgcn_mfma_f32_16x16x32_f16(af[i], bfr[j], acc[i][j], 0, 0, 0);
    __syncthreads();  // all reads done before next stage overwrites
  }

  // C/D layout (m89-verified): col = lane&15, row = quad*4 + reg.
#pragma unroll
  for (int i = 0; i < 4; ++i)
#pragma unroll
    for (int j = 0; j < 4; ++j)
#pragma unroll
      for (int r = 0; r < 4; ++r) {
        const int gm = m0 + wm * 64 + i * 16 + quad * 4 + r;
        const int gn = n0 + wn * 64 + j * 16 + m15;
        const float v = acc[i][j][r];
        if (OUT_MODE == 2) ((float*)Cg)[(size_t)gm * N + gn] = v;
        else               ((unsigned short*)Cg)[(size_t)gm * N + gn] = f2h(v);
      }
}

// ---------------------------------------------------------------------------
// elementwise fp32 -> fp16 (hidden pre-convert), 4 elems/thread.
// ---------------------------------------------------------------------------
__global__ __launch_bounds__(256) void cvt_f32_f16(const float* __restrict__ in,
                                                   unsigned short* __restrict__ out, int n4) {
  const int i = blockIdx.x * 256 + threadIdx.x;
  if (i >= n4) return;
  const float4 v = ((const float4*)in)[i];
  ushort4 o = {f2h(v.x), f2h(v.y), f2h(v.z), f2h(v.w)};
  ((ushort4*)out)[i] = o;
}

// ---------------------------------------------------------------------------
// transpose + convert: out_f16[C][R] = in_f32[R][C]. 64x64 tiles.
// ---------------------------------------------------------------------------
__global__ __launch_bounds__(256) void transpose_f2h(const float* __restrict__ in,
                                                     unsigned short* __restrict__ out,
                                                     int R, int C) {
  __shared__ float tile[64 * 68];
  const int r0 = blockIdx.y * 64, c0 = blockIdx.x * 64;
  const int t = threadIdx.x;
#pragma unroll
  for (int p = 0; p < 4; ++p) {
    const int idx = t + p * 256;
    const int rr = idx >> 4, cc = (idx & 15) * 4;
    *(float4*)&tile[rr * 68 + cc] = *(const float4*)&in[(size_t)(r0 + rr) * C + c0 + cc];
  }
  __syncthreads();
#pragma unroll
  for (int p = 0; p < 2; ++p) {
    const int idx = t + p * 256;
    const int dr = idx >> 3, sc = (idx & 7) * 8;
    union { uint4 v; unsigned short s[8]; } o;
#pragma unroll
    for (int e = 0; e < 8; ++e) o.s[e] = f2h(tile[(sc + e) * 68 + dr]);
    *(uint4*)&out[(size_t)(c0 + dr) * R + r0 + sc] = o.v;
  }
}

// ---------------------------------------------------------------------------
// Fused per-head RMSNorm + RoPE. One block per token.
// ---------------------------------------------------------------------------
__global__ __launch_bounds__(256) void normrope(const unsigned short* __restrict__ qkv,
                                                const int* __restrict__ pos,
                                                const float* __restrict__ qw,
                                                const float* __restrict__ kw,
                                                unsigned short* __restrict__ Qh,
                                                unsigned short* __restrict__ Kh,
                                                unsigned short* __restrict__ Vh) {
  const int tok = blockIdx.x;
  const int b = tok >> 11, s = tok & 2047;
  const int t = threadIdx.x, w = t >> 6, lane = t & 63;
  const float p = (float)pos[tok];
  const int dbase = lane * 4;

  for (int it = 0; it < 3; ++it) {
    const int slot = it * 4 + w;
    const unsigned short* src = qkv + (size_t)tok * NQKV + slot * 256 + dbase;
    union { uint2 u; _Float16 h[4]; } rd;
    rd.u = *(const uint2*)src;
    float y[4];
#pragma unroll
    for (int e = 0; e < 4; ++e) y[e] = (float)rd.h[e];
    float ssq = y[0] * y[0] + y[1] * y[1] + y[2] * y[2] + y[3] * y[3];
#pragma unroll
    for (int off = 1; off < 64; off <<= 1) ssq += __shfl_xor(ssq, off);
    const float rn = rsqrtf(ssq * (1.f / 256.f) + 1e-6f);

    if (slot < 8) {
#pragma unroll
      for (int e = 0; e < 4; ++e) y[e] *= rn * qw[dbase + e];
    } else if (slot < 10) {
#pragma unroll
      for (int e = 0; e < 4; ++e) y[e] *= rn * kw[dbase + e];
    } else {
#pragma unroll
      for (int e = 0; e < 4; ++e) y[e] *= rn;
    }

    unsigned short* dst;
    if (slot < 8)       dst = Qh + ((size_t)(b * NH + slot) * SB + s) * HD + dbase;
    else if (slot < 10) dst = Kh + ((size_t)(b * NKV + slot - 8) * SB + s) * HD + dbase;
    else                dst = Vh + ((size_t)(b * NKV + slot - 10) * SB + s) * HD + dbase;

    float outv[4];
    if (slot < 10) {
      const int i0 = dbase & 127;
      const bool lo = (lane < 32);
#pragma unroll
      for (int e = 0; e < 4; ++e) {
        const float partner = __shfl_xor(y[e], 32);
        const float invf = expf(-(float)(i0 + e) * 0.10793368f);  // 1e6^(-j/128)
        const float fr = p * invf;
        const float cv = cosf(fr), sv = sinf(fr);
        outv[e] = lo ? (y[e] * cv - partner * sv) : (y[e] * cv + partner * sv);
      }
    } else {
#pragma unroll
      for (int e = 0; e < 4; ++e) outv[e] = y[e];
    }
    union { uint2 u; _Float16 h[4]; } wr;
#pragma unroll
    for (int e = 0; e < 4; ++e) wr.h[e] = (_Float16)outv[e];
    *(uint2*)dst = wr.u;
  }
}

// ---------------------------------------------------------------------------
// 16-bit transpose: out[C][R] = in[R][C], batched. 64x64 LDS tiles.
// ---------------------------------------------------------------------------
__global__ __launch_bounds__(256) void transpose_u16(const unsigned short* __restrict__ in,
                                                     unsigned short* __restrict__ out,
                                                     int R, int C, size_t ibs, size_t obs) {
  __shared__ unsigned short tile[64 * 72];
  const unsigned short* ib = in + blockIdx.z * ibs;
  unsigned short* ob = out + blockIdx.z * obs;
  const int r0 = blockIdx.y * 64, c0 = blockIdx.x * 64;
  const int t = threadIdx.x;
#pragma unroll
  for (int pck = 0; pck < 2; ++pck) {
    const int c = t + pck * 256;
    const int rr = c >> 3, cc = (c & 7) * 8;
    *(uint4*)&tile[rr * 72 + cc] = *(const uint4*)&ib[(size_t)(r0 + rr) * C + c0 + cc];
  }
  __syncthreads();
#pragma unroll
  for (int pck = 0; pck < 2; ++pck) {
    const int c = t + pck * 256;
    const int dr = c >> 3, sc = (c & 7) * 8;
    union { uint4 v; unsigned short s[8]; } o;
#pragma unroll
    for (int e = 0; e < 8; ++e) o.s[e] = tile[(sc + e) * 72 + dr];
    *(uint4*)&ob[(size_t)(c0 + dr) * R + r0 + sc] = o.v;
  }
}

// ---------------------------------------------------------------------------
// Flash attention v4 (causal, no scale). Block = 4 waves, processes the q-tile
// PAIR (qa, 31-qa) sequentially -> uniform 33 64-key tiles per block; grid 256
// = 1 block/CU (no tail). K/V double-buffered in LDS (137KB): stage(t+1)
// issued before compute(t); single __syncthreads per tile at loop end, whose
// vmcnt(0) drain overlaps ~1.6k cycles of compute. fp16 MFMA, fp32 softmax.
// ---------------------------------------------------------------------------
__global__ __launch_bounds__(256) void flash_attn(const unsigned short* __restrict__ Qh,
                                                  const unsigned short* __restrict__ Kh,
                                                  const unsigned short* __restrict__ Vt,  // [B][NKV][D][S]
                                                  unsigned short* __restrict__ attn) {    // fp16 [B*S][NH*HD]
  __shared__ unsigned short Ksh[2][64 * 256];   // [key][d] flat, swizzled 16B chunks
  __shared__ unsigned short Vsh[2][256 * 64];   // [d][key] flat, swizzled 16B chunks
  __shared__ _Float16 Psh[4][16 * 72];          // per-wave 16 q x 64 keys (+8 pad)
  const int pairi = blockIdx.x;  // 0..15
  const int h = blockIdx.y, b = blockIdx.z;
  const int kv = h >> 2;
  const int t = threadIdx.x, w = t >> 6, lane = t & 63;
  const int quad = lane >> 4, m15 = lane & 15;

  const unsigned short* Kb = Kh + (size_t)(b * NKV + kv) * SB * HD;
  const unsigned short* Vb = Vt + (size_t)(b * NKV + kv) * HD * SB;

  // staging geometry (per thread, per 4KB shot)
  const int krow = t >> 5, kchunk = t & 31;
  const int vrow = t >> 3, vchunk = t & 7;

  const f32x4 vz = {0.f, 0.f, 0.f, 0.f};

  for (int jb = 0; jb < 2; ++jb) {
    const int qt = jb ? (31 - pairi) : pairi;
    const int q0 = qt * 64, qw0 = q0 + w * 16;

    // Q fragments: A[m=lane&15][k=quad*8+j]
    f16x8 aq[8];
    const unsigned short* qb = Qh + ((size_t)(b * NH + h) * SB + qw0 + m15) * HD + quad * 8;
#pragma unroll
    for (int ks = 0; ks < 8; ++ks) aq[ks] = *(const f16x8*)(qb + ks * 32);

    f32x4 o[16];
#pragma unroll
    for (int i = 0; i < 16; ++i) o[i] = vz;
    float mrow[4] = {-1e30f, -1e30f, -1e30f, -1e30f};
    float lrow[4] = {0.f, 0.f, 0.f, 0.f};

    const int nkt = (q0 + 64) >> 6;

    // prologue: stage tile 0 into buffer 0
#pragma unroll
    for (int shot = 0; shot < 8; ++shot) {
      const int r = krow + 8 * shot;
      async_copy16(Kb + (size_t)r * HD + ((kchunk ^ (r & 7)) * 8),
                   &Ksh[0][2048 * shot + t * 8]);
    }
#pragma unroll
    for (int shot = 0; shot < 8; ++shot) {
      const int d = vrow + 32 * shot;
      async_copy16(Vb + (size_t)d * SB + ((vchunk ^ (d & 7)) * 8),
                   &Vsh[0][2048 * shot + t * 8]);
    }
    __syncthreads();  // drain: tile 0 ready

    for (int kt = 0; kt < nkt; ++kt) {
      const int k0 = kt * 64;
      const int par = kt & 1;

      // stage tile kt+1 into the other buffer (drained by loop-end barrier)
      if (kt + 1 < nkt) {
        const int kn = k0 + 64;
        const int pn = par ^ 1;
#pragma unroll
        for (int shot = 0; shot < 8; ++shot) {
          const int r = krow + 8 * shot;
          async_copy16(Kb + (size_t)(kn + r) * HD + ((kchunk ^ (r & 7)) * 8),
                       &Ksh[pn][2048 * shot + t * 8]);
        }
#pragma unroll
        for (int shot = 0; shot < 8; ++shot) {
          const int d = vrow + 32 * shot;
          async_copy16(Vb + (size_t)d * SB + kn + ((vchunk ^ (d & 7)) * 8),
                       &Vsh[pn][2048 * shot + t * 8]);
        }
      }

      const unsigned short* KB = &Ksh[par][0];
      const unsigned short* VB = &Vsh[par][0];

      // ---- scores S[16 q][64 keys]: 4 groups of 16 keys ----
      f32x4 sv[4];
#pragma unroll
      for (int g = 0; g < 4; ++g) sv[g] = vz;
#pragma unroll
      for (int g = 0; g < 4; ++g) {
        const int key = g * 16 + m15;
        const unsigned short* kr = &KB[key * 256];
        const int sw = (key & 7);
#pragma unroll
        for (int ks = 0; ks < 8; ++ks) {
          const f16x8 bk = *(const f16x8*)&kr[((4 * ks + quad) ^ sw) * 8];
          sv[g] = __builtin_amdgcn_mfma_f32_16x16x32_f16(aq[ks], bk, sv[g], 0, 0, 0);
        }
      }

      // ---- online softmax over 64 cols (mask only in final tile) ----
      const bool last = (kt == nkt - 1);
#pragma unroll
      for (int r = 0; r < 4; ++r) {
        const int q = qw0 + quad * 4 + r;
        float s[4];
#pragma unroll
        for (int g = 0; g < 4; ++g) {
          s[g] = sv[g][r];
          if (last && (k0 + g * 16 + m15) > q) s[g] = -3.0e38f;
        }
        float tm = fmaxf(fmaxf(s[0], s[1]), fmaxf(s[2], s[3]));
#pragma unroll
        for (int off = 1; off < 16; off <<= 1) tm = fmaxf(tm, __shfl_xor(tm, off));
        const float mnew = fmaxf(mrow[r], tm);
        const float alpha = __expf(mrow[r] - mnew);
        float p[4], rs = 0.f;
#pragma unroll
        for (int g = 0; g < 4; ++g) { p[g] = __expf(s[g] - mnew); rs += p[g]; }
#pragma unroll
        for (int off = 1; off < 16; off <<= 1) rs += __shfl_xor(rs, off);
        lrow[r] = lrow[r] * alpha + rs;
        mrow[r] = mnew;
#pragma unroll
        for (int dbi = 0; dbi < 16; ++dbi) o[dbi][r] *= alpha;
        _Float16* pr = &Psh[w][(quad * 4 + r) * 72];
#pragma unroll
        for (int g = 0; g < 4; ++g) pr[g * 16 + m15] = (_Float16)p[g];
      }

      // ---- PV (same-wave LDS in-order; no barrier needed for Psh) ----
      asm volatile("" ::: "memory");
#pragma unroll
      for (int c = 0; c < 2; ++c) {
        const f16x8 ap = *(const f16x8*)&Psh[w][m15 * 72 + c * 32 + quad * 8];
#pragma unroll
        for (int dbi = 0; dbi < 16; ++dbi) {
          const int d = dbi * 16 + m15;
          const f16x8 bv = *(const f16x8*)&VB[d * 64 + (((4 * c + quad) ^ (d & 7)) * 8)];
          o[dbi] = __builtin_amdgcn_mfma_f32_16x16x32_f16(ap, bv, o[dbi], 0, 0, 0);
        }
      }

      __syncthreads();  // drains stage(kt+1) vmcnt + guards buffer reuse
    }

    float inv[4];
#pragma unroll
    for (int r = 0; r < 4; ++r) inv[r] = 1.0f / lrow[r];
#pragma unroll
    for (int dbi = 0; dbi < 16; ++dbi)
#pragma unroll
      for (int r = 0; r < 4; ++r) {
        const int q = qw0 + quad * 4 + r;
        const int col = h * HD + dbi * 16 + m15;
        attn[(size_t)(b * SB + q) * (NH * HD) + col] = f2h(o[dbi][r] * inv[r]);
      }
  }
}

// ---------------------------------------------------------------------------
// workspace layout (bytes), total 60 MiB with lifetime-based reuse.
// ---------------------------------------------------------------------------
static constexpr size_t OFF_HB   = 0;
static constexpr size_t OFF_QH   = 0;                      // 16,777,216
static constexpr size_t OFF_W1T  = 16777216;               // 12,582,912
static constexpr size_t OFF_KH   = 16777216;               //  4,194,304
static constexpr size_t OFF_VH   = 20971520;               //  4,194,304
static constexpr size_t OFF_VT   = 25165824;               //  4,194,304
static constexpr size_t OFF_WOT  = 29360128;               //  8,388,608
static constexpr size_t OFF_QKV  = 37748736;               // 25,165,824 -> 62,914,560
static constexpr size_t OFF_ATTN = OFF_QKV;                // 16,777,216 (reuse)

extern "C" void kernel_launch(void* const* d_in, const int* in_sizes, int n_in,
                              void* d_out, int out_size, void* d_ws, size_t ws_size,
                              hipStream_t stream) {
  const float* hidden    = (const float*)d_in[0];
  const int*   positions = (const int*)d_in[1];
  const float* w_qkv     = (const float*)d_in[2];
  const float* w_o       = (const float*)d_in[3];
  const float* qw        = (const float*)d_in[4];
  const float* kw        = (const float*)d_in[5];
  float* out = (float*)d_out;
  char* ws = (char*)d_ws;

  unsigned short* hb    = (unsigned short*)(ws + OFF_HB);
  unsigned short* wqkvT = (unsigned short*)(ws + OFF_W1T);
  unsigned short* woT   = (unsigned short*)(ws + OFF_WOT);
  unsigned short* qkvb  = (unsigned short*)(ws + OFF_QKV);
  unsigned short* attnb = (unsigned short*)(ws + OFF_ATTN);
  unsigned short* Qhb   = (unsigned short*)(ws + OFF_QH);
  unsigned short* Khb   = (unsigned short*)(ws + OFF_KH);
  unsigned short* Vhb   = (unsigned short*)(ws + OFF_VH);
  unsigned short* Vtb   = (unsigned short*)(ws + OFF_VT);

  cvt_f32_f16<<<dim3((MTOK * HID / 4 + 255) / 256), 256, 0, stream>>>(hidden, hb, MTOK * HID / 4);
  transpose_f2h<<<dim3(NQKV / 64, HID / 64), 256, 0, stream>>>(w_qkv, wqkvT, HID, NQKV);
  transpose_f2h<<<dim3(HID / 64, HID / 64), 256, 0, stream>>>(w_o, woT, HID, HID);

  gemm_bt<0><<<dim3(NQKV / 128, MTOK / 128), 256, 0, stream>>>(hb, wqkvT, qkvb, MTOK, NQKV, HID);

  normrope<<<dim3(MTOK), 256, 0, stream>>>(qkvb, positions, qw, kw, Qhb, Khb, Vhb);

  transpose_u16<<<dim3(HD / 64, SB / 64, BB * NKV), 256, 0, stream>>>(Vhb, Vtb, SB, HD,
                                                                     (size_t)SB * HD, (size_t)SB * HD);

  flash_attn<<<dim3(16, NH, BB), 256, 0, stream>>>(Qhb, Khb, Vtb, attnb);

  gemm_bt<2><<<dim3(HID / 128, MTOK / 128), 256, 0, stream>>>(attnb, woT, out, MTOK, HID, HID);
}